// Round 1
// baseline (4016.805 us; speedup 1.0000x reference)
//
#include <hip/hip_runtime.h>

// ---------------------------------------------------------------------------
// Encoder: feature/temporal regression + temporal-decay LSTM scan + L1 loss
// B=512 T=128 F=128 H=256.  Outputs: h[512,256], c[512,256], loss (fp32).
//
// Structure:
//   kprep  : pack W_cat=[W_ih|W_hh] fp16 [1024][512], out_W fp16, masked/
//            transposed regression weights, zero flags/accums.
//   kdenom : denom_inv[t] = 1/(sum masks[:,t,:] + 1e-5)
//   k1     : values_hat (both regressions + mask blend) -> x_all fp16 [T][B][256]
//   k2     : gamma = exp(-|deltas W_d^T + b_d|)        -> g_all fp16 [T][B][256]
//   kscan  : persistent 256-WG scan. 32 row-tiles x 8 col-chunks; W slice in
//            LDS (loaded once, reused 127 steps); c in registers; h ping-pong
//            through global fp16 with per-group atomic-flag sync. Loss term
//            t-1 fused into step t (reuses the h fragments already loaded).
//   kepi   : final loss term (t=126) from d_out h (fp32).
//   kfin   : loss = accum + num_final * dinv[127].
// ---------------------------------------------------------------------------

typedef _Float16 f16;
typedef _Float16 half8 __attribute__((ext_vector_type(8)));
typedef float f32x4 __attribute__((ext_vector_type(4)));

#define B_ 512
#define T_ 128
#define F_ 128
#define H_ 256
#define NSTEP 127
#define KP 520     // padded LDS row stride (elems) for W slice: 16B-aligned rows, bank shift 4
#define OWP 264    // padded LDS row stride for out_W slice

__device__ __forceinline__ float sigm(float x){ return 1.f/(1.f + __expf(-x)); }
__device__ __forceinline__ float tanh_(float x){
  float e = __expf(-2.f*fabsf(x));
  float t = (1.f - e)/(1.f + e);
  return x >= 0.f ? t : -t;
}

// ---------------------------------------------------------------------------
__global__ void kprep(const float* __restrict__ Wih, const float* __restrict__ Whh,
                      const float* __restrict__ outW,
                      const float* __restrict__ featW, const float* __restrict__ tempW,
                      const float* __restrict__ decW,
                      f16* __restrict__ Wt, f16* __restrict__ oWh,
                      float* __restrict__ fWT, float* __restrict__ tWm,
                      float* __restrict__ dWT, unsigned int* __restrict__ flags,
                      float* __restrict__ accums)
{
  int idx = blockIdx.x*256 + threadIdx.x;
  int stride = gridDim.x*256;
  // W_cat[zc][k]: k<256 -> W_ih[zc][k] (inp = [values_hat, masks]); k>=256 -> W_hh
  for (int i = idx; i < 1024*512; i += stride){
    int zc = i >> 9, k = i & 511;
    float w = (k < 256) ? Wih[zc*256 + k] : Whh[zc*256 + k - 256];
    Wt[i] = (f16)w;
  }
  for (int i = idx; i < 128*256; i += stride) oWh[i] = (f16)outW[i];
  // fWT[g][f] = feat_W[f][g] with diag zeroed (einsum 'btf,gf->btg' masked)
  for (int i = idx; i < 128*128; i += stride){
    int g = i >> 7, f = i & 127;
    fWT[i] = (f == g) ? 0.f : featW[f*128 + g];
  }
  for (int i = idx; i < 128*128; i += stride){
    int t = i >> 7, s = i & 127;
    tWm[i] = (s == t) ? 0.f : tempW[i];
  }
  // dWT[f][h] = decay_W[h][f]
  for (int i = idx; i < 128*256; i += stride){
    int f = i >> 8, h = i & 255;
    dWT[i] = decW[h*128 + f];
  }
  for (int i = idx; i < 128*32; i += stride) flags[i] = 0u;
  if (idx < 2) accums[idx] = 0.f;
}

// ---------------------------------------------------------------------------
__global__ __launch_bounds__(256) void kdenom(const float* __restrict__ masks,
                                              float* __restrict__ dinv)
{
  int t = blockIdx.x;
  __shared__ float red[256];
  float s = 0.f;
  for (int i = threadIdx.x; i < B_*F_; i += 256){
    int b = i >> 7, f = i & 127;
    s += masks[((size_t)b << 14) + (t << 7) + f];
  }
  red[threadIdx.x] = s; __syncthreads();
  for (int o = 128; o > 0; o >>= 1){
    if (threadIdx.x < o) red[threadIdx.x] += red[threadIdx.x + o];
    __syncthreads();
  }
  if (threadIdx.x == 0) dinv[t] = 1.f/(red[0] + 1e-5f);
}

// ---------------------------------------------------------------------------
// values_hat: vhat[b,t,f] = sum_g v[b,t,g]*fWT[g][f] + sum_s v[b,s,f]*tWm[t][s]
//                           + feat_b[f] + temp_b[t]
// x = v*m + vhat*(1-m); x_all[t][b][0:128]=x, [128:256]=m
__global__ __launch_bounds__(256) void k1(
    const float* __restrict__ values, const float* __restrict__ masks,
    const float* __restrict__ fWT, const float* __restrict__ tWm,
    const float* __restrict__ featb, const float* __restrict__ tempb,
    f16* __restrict__ x_all)
{
  __shared__ float vbuf[128][128];   // 64 KB, 2 blocks/CU
  const int b = blockIdx.x, tid = threadIdx.x;
  const float* vb = values + ((size_t)b << 14);
  for (int i = tid; i < 128*128; i += 256) (&vbuf[0][0])[i] = vb[i];
  __syncthreads();
  const int f = tid & 127, th = tid >> 7;
  const float fb = featb[f];
  for (int tt = 0; tt < 4; ++tt){
    const int t0 = th*64 + tt*16;
    float acc[16];
#pragma unroll
    for (int i = 0; i < 16; ++i) acc[i] = 0.f;
    for (int g = 0; g < 128; ++g){
      float w = fWT[(g<<7) + f];
#pragma unroll
      for (int i = 0; i < 16; ++i) acc[i] += vbuf[t0+i][g] * w;
    }
    for (int s = 0; s < 128; ++s){
      float v = vbuf[s][f];
#pragma unroll
      for (int i = 0; i < 16; ++i) acc[i] += v * tWm[((t0+i)<<7) + s];
    }
#pragma unroll
    for (int i = 0; i < 16; ++i){
      int t = t0 + i;
      float vh = acc[i] + fb + tempb[t];
      float m = masks[((size_t)b << 14) + (t << 7) + f];
      float v = vbuf[t][f];
      float x = v*m + vh*(1.f - m);
      size_t o = (((size_t)t << 9) + b) << 8;
      x_all[o + f] = (f16)x;
      x_all[o + 128 + f] = (f16)m;
    }
  }
}

// ---------------------------------------------------------------------------
__global__ __launch_bounds__(256) void k2(
    const float* __restrict__ deltas, const float* __restrict__ dWT,
    const float* __restrict__ decb, f16* __restrict__ g_all)
{
  __shared__ float dbuf[128][128];
  const int b = blockIdx.x, tid = threadIdx.x;
  const float* dp = deltas + ((size_t)b << 14);
  for (int i = tid; i < 128*128; i += 256) (&dbuf[0][0])[i] = dp[i];
  __syncthreads();
  const float bias = decb[tid];
  for (int tt = 0; tt < 8; ++tt){
    float acc[16];
#pragma unroll
    for (int i = 0; i < 16; ++i) acc[i] = 0.f;
    for (int fch = 0; fch < 128; ++fch){
      float w = dWT[(fch<<8) + tid];
#pragma unroll
      for (int i = 0; i < 16; ++i) acc[i] += dbuf[tt*16+i][fch] * w;
    }
#pragma unroll
    for (int i = 0; i < 16; ++i){
      int t = tt*16 + i;
      float gv = __expf(-fabsf(acc[i] + bias));
      g_all[((((size_t)t << 9) + b) << 8) + tid] = (f16)gv;
    }
  }
}

// ---------------------------------------------------------------------------
// Persistent scan. grid=256: gid=blockIdx&31 (row tile, 16 rows), q=blockIdx>>5
// (col chunk, 32 h-cols => 128 z-cols across 4 gates). 1 WG/CU (LDS-forced).
__global__ __launch_bounds__(256, 1) void kscan(
    const f16* __restrict__ x_all, const f16* __restrict__ g_all,
    const f16* __restrict__ Wt, const f16* __restrict__ oWh,
    const float* __restrict__ bih, const float* __restrict__ bhh,
    const float* __restrict__ outb,
    const float* __restrict__ values, const float* __restrict__ masks,
    const float* __restrict__ dinv,
    f16* __restrict__ h_buf, unsigned int* __restrict__ flags,
    float* __restrict__ loss_accum, float* __restrict__ d_out)
{
  extern __shared__ char smem[];
  f16* Wl  = (f16*)smem;                                // [128][KP]
  f16* oWl = (f16*)(smem + 128*KP*2);                   // [16][OWP]
  float* gl = (float*)(smem + 128*KP*2 + 16*OWP*2);     // [64][33] gate exchange

  const int tid = threadIdx.x;
  const int gid = blockIdx.x & 31;
  const int q   = blockIdx.x >> 5;
  const int b_base = gid << 4;
  const int j_base = q << 5;

  // load W slice: LDS row r (r>>5 = gate, r&31 = jj) <-> zcol = gate*256 + j_base + jj
  for (int i = tid; i < 128*128; i += 256){
    int r = i >> 7, c4 = (i & 127) << 2;
    int zc = ((r >> 5) << 8) + j_base + (r & 31);
    *(uint2*)(Wl + r*KP + c4) = *(const uint2*)(Wt + zc*512 + c4);
  }
  // out_W slice: 16 out-cols [q*16 .. q*16+16)
  for (int i = tid; i < 16*64; i += 256){
    int r = i >> 6, c4 = (i & 63) << 2;
    *(uint2*)(oWl + r*OWP + c4) = *(const uint2*)(oWh + (q*16 + r)*256 + c4);
  }
  __syncthreads();

  const int wv = tid >> 6;        // wave = gate (0:i 1:f 2:g 3:o)
  const int lane = tid & 63;
  const int lrow = lane & 15;
  const int lq = lane >> 4;
  const int arow = b_base + lrow; // A-fragment row (batch)

  const float bias0 = bih[(wv<<8) + j_base + lrow]      + bhh[(wv<<8) + j_base + lrow];
  const float bias1 = bih[(wv<<8) + j_base + 16 + lrow] + bhh[(wv<<8) + j_base + 16 + lrow];
  const float ob = outb[(q<<4) + lrow];

  float c0 = 0.f, c1 = 0.f;     // cell state, register-resident all 127 steps
  float lossAcc = 0.f;

  const f16* wb0 = Wl + ((wv<<5) + lrow)*KP + (lq<<3);
  const f16* wb1 = wb0 + 16*KP;

  for (int t = 0; t < NSTEP; ++t){
    if (t > 0){
      if (tid == 0){
        int guard = 0;
        while (__hip_atomic_load(&flags[(t<<5) + gid], __ATOMIC_ACQUIRE,
                                 __HIP_MEMORY_SCOPE_AGENT) < 8u && guard < 100000){
          ++guard;
          __builtin_amdgcn_s_sleep(2);
        }
      }
      __syncthreads();
    }

    f32x4 acc0 = {0.f,0.f,0.f,0.f}, acc1 = {0.f,0.f,0.f,0.f}, accL = {0.f,0.f,0.f,0.f};

    // x half (K = 0..255): inp = [values_hat, masks]
    const f16* xp = x_all + (((size_t)t*B_ + arow) << 8) + (lq << 3);
#pragma unroll
    for (int kk = 0; kk < 8; ++kk){
      half8 a  = *(const half8*)(xp + (kk<<5));
      half8 b0 = *(const half8*)(wb0 + (kk<<5));
      half8 b1 = *(const half8*)(wb1 + (kk<<5));
      acc0 = __builtin_amdgcn_mfma_f32_16x16x32_f16(a, b0, acc0, 0,0,0);
      acc1 = __builtin_amdgcn_mfma_f32_16x16x32_f16(a, b1, acc1, 0,0,0);
    }

    if (t > 0){
      // h half (K = 256..511): A = h_t * gamma_t ; raw h feeds loss term t-1
      const f16* hp = h_buf + ((((t&1)*B_) + arow) << 8) + (lq << 3);
      const f16* gp = g_all + (((size_t)t*B_ + arow) << 8) + (lq << 3);
#pragma unroll
      for (int kk = 0; kk < 8; ++kk){
        half8 hr = *(const half8*)(hp + (kk<<5));
        half8 gg = *(const half8*)(gp + (kk<<5));
        if (wv == 0){
          half8 bo = *(const half8*)(oWl + lrow*OWP + (kk<<5) + (lq<<3));
          accL = __builtin_amdgcn_mfma_f32_16x16x32_f16(hr, bo, accL, 0,0,0);
        }
        half8 hg = hr * gg;
        half8 b0 = *(const half8*)(wb0 + 256 + (kk<<5));
        half8 b1 = *(const half8*)(wb1 + 256 + (kk<<5));
        acc0 = __builtin_amdgcn_mfma_f32_16x16x32_f16(hg, b0, acc0, 0,0,0);
        acc1 = __builtin_amdgcn_mfma_f32_16x16x32_f16(hg, b1, acc1, 0,0,0);
      }
      if (wv == 0){
        float dt = dinv[t];
#pragma unroll
        for (int r = 0; r < 4; ++r){
          int b = b_base + (lq<<2) + r;
          int f = (q<<4) + lrow;
          size_t o = ((size_t)b << 14) + (t << 7) + f;
          float ov = accL[r] + ob;
          lossAcc += fabsf(values[o] - ov) * masks[o] * dt;
        }
      }
    }

    // publish gates to LDS (C layout: row=(lane>>4)*4+r, col=lane&15)
#pragma unroll
    for (int r = 0; r < 4; ++r){
      int row = (lq<<2) + r;
      gl[((wv<<4) + row)*33 + lrow]      = acc0[r] + bias0;
      gl[((wv<<4) + row)*33 + 16 + lrow] = acc1[r] + bias1;
    }
    __syncthreads();

    // cell update: 512 elems [16 rows x 32 cols], 2 per thread
#pragma unroll
    for (int pp = 0; pp < 2; ++pp){
      int e = tid + (pp<<8);
      int row = e >> 5, col = e & 31;
      float zi = gl[row*33 + col];
      float zf = gl[(16+row)*33 + col];
      float zg = gl[(32+row)*33 + col];
      float zo = gl[(48+row)*33 + col];
      float cp = pp ? c1 : c0;
      float cn = sigm(zf)*cp + sigm(zi)*tanh_(zg);
      float hn = sigm(zo)*tanh_(cn);
      if (pp) c1 = cn; else c0 = cn;
      int b = b_base + row, j = j_base + col;
      if (t < NSTEP-1){
        h_buf[((((t+1)&1)*B_ + b) << 8) + j] = (f16)hn;
      } else {
        d_out[(b<<8) + j] = hn;               // h, fp32 from registers
        d_out[(1<<17) + (b<<8) + j] = cn;     // c
      }
    }

    if (t < NSTEP-1){
      __threadfence();
      __syncthreads();   // all threads' h stores + fences done; also protects gl reuse
      if (tid == 0)
        __hip_atomic_fetch_add(&flags[((t+1)<<5) + gid], 1u, __ATOMIC_RELEASE,
                               __HIP_MEMORY_SCOPE_AGENT);
    } else {
      __syncthreads();
    }
  }

  // loss terms 0..125 reduction (wave 0 holds them)
  if (wv == 0){
#pragma unroll
    for (int off = 32; off > 0; off >>= 1)
      lossAcc += __shfl_down(lossAcc, off, 64);
    if (lane == 0) atomicAdd(loss_accum, lossAcc);
  }
}

// ---------------------------------------------------------------------------
__global__ __launch_bounds__(256) void kepi(
    const float* __restrict__ h_out, const float* __restrict__ outW,
    const float* __restrict__ outb, const float* __restrict__ values,
    const float* __restrict__ masks, float* __restrict__ num_final)
{
  int idx = blockIdx.x*256 + threadIdx.x;   // 65536 = 512*128
  int b = idx >> 7, f = idx & 127;
  const float* hr = h_out + (b << 8);
  const float* wr = outW + (f << 8);
  float s0 = 0.f, s1 = 0.f, s2 = 0.f, s3 = 0.f;
  for (int j = 0; j < 256; j += 4){
    s0 += hr[j]   * wr[j];
    s1 += hr[j+1] * wr[j+1];
    s2 += hr[j+2] * wr[j+2];
    s3 += hr[j+3] * wr[j+3];
  }
  float s = s0 + s1 + s2 + s3 + outb[f];
  size_t o = ((size_t)b << 14) + (127 << 7) + f;
  float term = fabsf(values[o] - s) * masks[o];
  __shared__ float red[256];
  red[threadIdx.x] = term; __syncthreads();
  for (int off = 128; off > 0; off >>= 1){
    if (threadIdx.x < off) red[threadIdx.x] += red[threadIdx.x + off];
    __syncthreads();
  }
  if (threadIdx.x == 0) atomicAdd(num_final, red[0]);
}

__global__ void kfin(const float* __restrict__ loss_accum,
                     const float* __restrict__ num_final,
                     const float* __restrict__ dinv, float* __restrict__ d_out)
{
  d_out[1<<18] = loss_accum[0] + num_final[0] * dinv[127];
}

// ---------------------------------------------------------------------------
extern "C" void kernel_launch(void* const* d_in, const int* in_sizes, int n_in,
                              void* d_out, int out_size, void* d_ws, size_t ws_size,
                              hipStream_t stream)
{
  const float* values = (const float*)d_in[0];
  const float* masks  = (const float*)d_in[1];
  const float* deltas = (const float*)d_in[2];
  const float* featW  = (const float*)d_in[3];
  const float* featb  = (const float*)d_in[4];
  const float* tempW  = (const float*)d_in[5];
  const float* tempb  = (const float*)d_in[6];
  const float* decW   = (const float*)d_in[7];
  const float* decb   = (const float*)d_in[8];
  const float* Wih    = (const float*)d_in[9];
  const float* Whh    = (const float*)d_in[10];
  const float* bih    = (const float*)d_in[11];
  const float* bhh    = (const float*)d_in[12];
  const float* outW   = (const float*)d_in[13];
  const float* outb   = (const float*)d_in[14];
  float* out = (float*)d_out;
  char* ws = (char*)d_ws;

  f16* Wt    = (f16*)(ws + 0);                 // 1 MB
  f16* oWh   = (f16*)(ws + 1048576);           // 64 KB
  float* fWT = (float*)(ws + 1114112);         // 64 KB
  float* tWm = (float*)(ws + 1179648);         // 64 KB
  float* dWT = (float*)(ws + 1245184);         // 128 KB
  float* dinv = (float*)(ws + 1376256);        // 512 B
  unsigned int* flags = (unsigned int*)(ws + 1376768);  // 16 KB
  float* accums = (float*)(ws + 1393152);      // [0]=loss_accum [1]=num_final
  f16* h_buf = (f16*)(ws + 1393664);           // 512 KB ping-pong
  f16* x_all = (f16*)(ws + 1917952);           // 32 MB
  f16* g_all = (f16*)(ws + 35472384);          // 32 MB  (end ~69 MB)

  kprep<<<256, 256, 0, stream>>>(Wih, Whh, outW, featW, tempW, decW,
                                 Wt, oWh, fWT, tWm, dWT, flags, accums);
  kdenom<<<128, 256, 0, stream>>>(masks, dinv);
  k1<<<512, 256, 0, stream>>>(values, masks, fWT, tWm, featb, tempb, x_all);
  k2<<<512, 256, 0, stream>>>(deltas, dWT, decb, g_all);

  const int SLDS = 128*KP*2 + 16*OWP*2 + 64*33*4;   // 150016 B
  hipFuncSetAttribute((const void*)kscan, hipFuncAttributeMaxDynamicSharedMemorySize, SLDS);
  kscan<<<256, 256, SLDS, stream>>>(x_all, g_all, Wt, oWh, bih, bhh, outb,
                                    values, masks, dinv, h_buf, flags,
                                    accums, out);

  kepi<<<256, 256, 0, stream>>>(out, outW, outb, values, masks, accums + 1);
  kfin<<<1, 1, 0, stream>>>(accums, accums + 1, dinv, out);
}

// Round 2
// 1492.613 us; speedup vs baseline: 2.6911x; 2.6911x over previous
//
#include <hip/hip_runtime.h>

// ---------------------------------------------------------------------------
// Encoder: feature/temporal regression + temporal-decay LSTM scan + L1 loss
// B=512 T=128 F=128 H=256.  Outputs: h[512,256], c[512,256], loss (fp32).
//
// R1 -> R2 change: kscan sync rework. Was: __threadfence() (agent seq_cst ->
// L2 wbl2/inv per WG per step) + ACQUIRE flag load per poll iteration (L2 inv
// per poll) + all 32 group flags packed into 2 cache lines (256 agents
// hammering 2 lines). Now: flags padded to 1 line/(t,gid), RELAXED polls with
// s_sleep backoff, exactly ONE acquire fence per step on poll success (keeps
// the L1 invalidate that makes plain h_buf loads coherent within the XCD),
// producer signals with RELAXED fetch_add after __syncthreads (which drains
// vmcnt -> h stores visible in same-XCD L2 before the flag RMW issues).
// ---------------------------------------------------------------------------

typedef _Float16 f16;
typedef _Float16 half8 __attribute__((ext_vector_type(8)));
typedef float f32x4 __attribute__((ext_vector_type(4)));

#define B_ 512
#define T_ 128
#define F_ 128
#define H_ 256
#define NSTEP 127
#define KP 520     // padded LDS row stride (elems) for W slice
#define OWP 264    // padded LDS row stride for out_W slice
#define FLAG_STRIDE 16   // dwords: one 64B line per (t,gid)

__device__ __forceinline__ float sigm(float x){ return 1.f/(1.f + __expf(-x)); }
__device__ __forceinline__ float tanh_(float x){
  float e = __expf(-2.f*fabsf(x));
  float t = (1.f - e)/(1.f + e);
  return x >= 0.f ? t : -t;
}

// ---------------------------------------------------------------------------
__global__ void kprep(const float* __restrict__ Wih, const float* __restrict__ Whh,
                      const float* __restrict__ outW,
                      const float* __restrict__ featW, const float* __restrict__ tempW,
                      const float* __restrict__ decW,
                      f16* __restrict__ Wt, f16* __restrict__ oWh,
                      float* __restrict__ fWT, float* __restrict__ tWm,
                      float* __restrict__ dWT, unsigned int* __restrict__ flags,
                      float* __restrict__ accums)
{
  int idx = blockIdx.x*256 + threadIdx.x;
  int stride = gridDim.x*256;
  // W_cat[zc][k]: k<256 -> W_ih[zc][k] (inp = [values_hat, masks]); k>=256 -> W_hh
  for (int i = idx; i < 1024*512; i += stride){
    int zc = i >> 9, k = i & 511;
    float w = (k < 256) ? Wih[zc*256 + k] : Whh[zc*256 + k - 256];
    Wt[i] = (f16)w;
  }
  for (int i = idx; i < 128*256; i += stride) oWh[i] = (f16)outW[i];
  // fWT[g][f] = feat_W[f][g] with diag zeroed (einsum 'btf,gf->btg' masked)
  for (int i = idx; i < 128*128; i += stride){
    int g = i >> 7, f = i & 127;
    fWT[i] = (f == g) ? 0.f : featW[f*128 + g];
  }
  for (int i = idx; i < 128*128; i += stride){
    int t = i >> 7, s = i & 127;
    tWm[i] = (s == t) ? 0.f : tempW[i];
  }
  // dWT[f][h] = decay_W[h][f]
  for (int i = idx; i < 128*256; i += stride){
    int f = i >> 8, h = i & 255;
    dWT[i] = decW[h*128 + f];
  }
  for (int i = idx; i < 128*32*FLAG_STRIDE; i += stride) flags[i] = 0u;
  if (idx < 2) accums[idx] = 0.f;
}

// ---------------------------------------------------------------------------
__global__ __launch_bounds__(256) void kdenom(const float* __restrict__ masks,
                                              float* __restrict__ dinv)
{
  int t = blockIdx.x;
  __shared__ float red[256];
  float s = 0.f;
  for (int i = threadIdx.x; i < B_*F_; i += 256){
    int b = i >> 7, f = i & 127;
    s += masks[((size_t)b << 14) + (t << 7) + f];
  }
  red[threadIdx.x] = s; __syncthreads();
  for (int o = 128; o > 0; o >>= 1){
    if (threadIdx.x < o) red[threadIdx.x] += red[threadIdx.x + o];
    __syncthreads();
  }
  if (threadIdx.x == 0) dinv[t] = 1.f/(red[0] + 1e-5f);
}

// ---------------------------------------------------------------------------
// values_hat: vhat[b,t,f] = sum_g v[b,t,g]*fWT[g][f] + sum_s v[b,s,f]*tWm[t][s]
//                           + feat_b[f] + temp_b[t]
// x = v*m + vhat*(1-m); x_all[t][b][0:128]=x, [128:256]=m
__global__ __launch_bounds__(256) void k1(
    const float* __restrict__ values, const float* __restrict__ masks,
    const float* __restrict__ fWT, const float* __restrict__ tWm,
    const float* __restrict__ featb, const float* __restrict__ tempb,
    f16* __restrict__ x_all)
{
  __shared__ float vbuf[128][128];   // 64 KB, 2 blocks/CU
  const int b = blockIdx.x, tid = threadIdx.x;
  const float* vb = values + ((size_t)b << 14);
  for (int i = tid; i < 128*128; i += 256) (&vbuf[0][0])[i] = vb[i];
  __syncthreads();
  const int f = tid & 127, th = tid >> 7;
  const float fb = featb[f];
  for (int tt = 0; tt < 4; ++tt){
    const int t0 = th*64 + tt*16;
    float acc[16];
#pragma unroll
    for (int i = 0; i < 16; ++i) acc[i] = 0.f;
    for (int g = 0; g < 128; ++g){
      float w = fWT[(g<<7) + f];
#pragma unroll
      for (int i = 0; i < 16; ++i) acc[i] += vbuf[t0+i][g] * w;
    }
    for (int s = 0; s < 128; ++s){
      float v = vbuf[s][f];
#pragma unroll
      for (int i = 0; i < 16; ++i) acc[i] += v * tWm[((t0+i)<<7) + s];
    }
#pragma unroll
    for (int i = 0; i < 16; ++i){
      int t = t0 + i;
      float vh = acc[i] + fb + tempb[t];
      float m = masks[((size_t)b << 14) + (t << 7) + f];
      float v = vbuf[t][f];
      float x = v*m + vh*(1.f - m);
      size_t o = (((size_t)t << 9) + b) << 8;
      x_all[o + f] = (f16)x;
      x_all[o + 128 + f] = (f16)m;
    }
  }
}

// ---------------------------------------------------------------------------
__global__ __launch_bounds__(256) void k2(
    const float* __restrict__ deltas, const float* __restrict__ dWT,
    const float* __restrict__ decb, f16* __restrict__ g_all)
{
  __shared__ float dbuf[128][128];
  const int b = blockIdx.x, tid = threadIdx.x;
  const float* dp = deltas + ((size_t)b << 14);
  for (int i = tid; i < 128*128; i += 256) (&dbuf[0][0])[i] = dp[i];
  __syncthreads();
  const float bias = decb[tid];
  for (int tt = 0; tt < 8; ++tt){
    float acc[16];
#pragma unroll
    for (int i = 0; i < 16; ++i) acc[i] = 0.f;
    for (int fch = 0; fch < 128; ++fch){
      float w = dWT[(fch<<8) + tid];
#pragma unroll
      for (int i = 0; i < 16; ++i) acc[i] += dbuf[tt*16+i][fch] * w;
    }
#pragma unroll
    for (int i = 0; i < 16; ++i){
      int t = tt*16 + i;
      float gv = __expf(-fabsf(acc[i] + bias));
      g_all[((((size_t)t << 9) + b) << 8) + tid] = (f16)gv;
    }
  }
}

// ---------------------------------------------------------------------------
// Persistent scan. grid=256: gid=blockIdx&31 (row tile, 16 rows), q=blockIdx>>5
// (col chunk, 32 h-cols => 128 z-cols across 4 gates). 1 WG/CU (LDS-forced).
// Group {gid, gid+32, ..., gid+224} lands on one XCD under round-robin
// blockIdx->XCD mapping (all ≡ gid mod 8) -> same-XCD L2 is the coherence
// point for h_buf; one acquire fence per step invalidates L1.
__global__ __launch_bounds__(256, 1) void kscan(
    const f16* __restrict__ x_all, const f16* __restrict__ g_all,
    const f16* __restrict__ Wt, const f16* __restrict__ oWh,
    const float* __restrict__ bih, const float* __restrict__ bhh,
    const float* __restrict__ outb,
    const float* __restrict__ values, const float* __restrict__ masks,
    const float* __restrict__ dinv,
    f16* __restrict__ h_buf, unsigned int* __restrict__ flags,
    float* __restrict__ loss_accum, float* __restrict__ d_out)
{
  extern __shared__ char smem[];
  f16* Wl  = (f16*)smem;                                // [128][KP]
  f16* oWl = (f16*)(smem + 128*KP*2);                   // [16][OWP]
  float* gl = (float*)(smem + 128*KP*2 + 16*OWP*2);     // [64][33] gate exchange

  const int tid = threadIdx.x;
  const int gid = blockIdx.x & 31;
  const int q   = blockIdx.x >> 5;
  const int b_base = gid << 4;
  const int j_base = q << 5;

  // load W slice: LDS row r (r>>5 = gate, r&31 = jj) <-> zcol = gate*256 + j_base + jj
  for (int i = tid; i < 128*128; i += 256){
    int r = i >> 7, c4 = (i & 127) << 2;
    int zc = ((r >> 5) << 8) + j_base + (r & 31);
    *(uint2*)(Wl + r*KP + c4) = *(const uint2*)(Wt + zc*512 + c4);
  }
  // out_W slice: 16 out-cols [q*16 .. q*16+16)
  for (int i = tid; i < 16*64; i += 256){
    int r = i >> 6, c4 = (i & 63) << 2;
    *(uint2*)(oWl + r*OWP + c4) = *(const uint2*)(oWh + (q*16 + r)*256 + c4);
  }
  __syncthreads();

  const int wv = tid >> 6;        // wave = gate (0:i 1:f 2:g 3:o)
  const int lane = tid & 63;
  const int lrow = lane & 15;
  const int lq = lane >> 4;
  const int arow = b_base + lrow; // A-fragment row (batch)

  const float bias0 = bih[(wv<<8) + j_base + lrow]      + bhh[(wv<<8) + j_base + lrow];
  const float bias1 = bih[(wv<<8) + j_base + 16 + lrow] + bhh[(wv<<8) + j_base + 16 + lrow];
  const float ob = outb[(q<<4) + lrow];

  float c0 = 0.f, c1 = 0.f;     // cell state, register-resident all 127 steps
  float lossAcc = 0.f;

  const f16* wb0 = Wl + ((wv<<5) + lrow)*KP + (lq<<3);
  const f16* wb1 = wb0 + 16*KP;

  for (int t = 0; t < NSTEP; ++t){
    if (t > 0){
      if (tid == 0){
        int guard = 0;
        while (__hip_atomic_load(&flags[((t<<5) + gid)*FLAG_STRIDE],
                                 __ATOMIC_RELAXED,
                                 __HIP_MEMORY_SCOPE_AGENT) < 8u && guard < 2000000){
          ++guard;
          __builtin_amdgcn_s_sleep(1);
        }
        // one acquire per step: orders h_buf loads after the flag, invalidates
        // this CU's L1 (shared by all 4 waves of the WG)
        __builtin_amdgcn_fence(__ATOMIC_ACQUIRE, "agent");
      }
      __syncthreads();
    }

    f32x4 acc0 = {0.f,0.f,0.f,0.f}, acc1 = {0.f,0.f,0.f,0.f}, accL = {0.f,0.f,0.f,0.f};

    // x half (K = 0..255): inp = [values_hat, masks]
    const f16* xp = x_all + (((size_t)t*B_ + arow) << 8) + (lq << 3);
#pragma unroll
    for (int kk = 0; kk < 8; ++kk){
      half8 a  = *(const half8*)(xp + (kk<<5));
      half8 b0 = *(const half8*)(wb0 + (kk<<5));
      half8 b1 = *(const half8*)(wb1 + (kk<<5));
      acc0 = __builtin_amdgcn_mfma_f32_16x16x32_f16(a, b0, acc0, 0,0,0);
      acc1 = __builtin_amdgcn_mfma_f32_16x16x32_f16(a, b1, acc1, 0,0,0);
    }

    if (t > 0){
      // h half (K = 256..511): A = h_t * gamma_t ; raw h feeds loss term t-1
      const f16* hp = h_buf + ((((t&1)*B_) + arow) << 8) + (lq << 3);
      const f16* gp = g_all + (((size_t)t*B_ + arow) << 8) + (lq << 3);
#pragma unroll
      for (int kk = 0; kk < 8; ++kk){
        half8 hr = *(const half8*)(hp + (kk<<5));
        half8 gg = *(const half8*)(gp + (kk<<5));
        if (wv == 0){
          half8 bo = *(const half8*)(oWl + lrow*OWP + (kk<<5) + (lq<<3));
          accL = __builtin_amdgcn_mfma_f32_16x16x32_f16(hr, bo, accL, 0,0,0);
        }
        half8 hg = hr * gg;
        half8 b0 = *(const half8*)(wb0 + 256 + (kk<<5));
        half8 b1 = *(const half8*)(wb1 + 256 + (kk<<5));
        acc0 = __builtin_amdgcn_mfma_f32_16x16x32_f16(hg, b0, acc0, 0,0,0);
        acc1 = __builtin_amdgcn_mfma_f32_16x16x32_f16(hg, b1, acc1, 0,0,0);
      }
      if (wv == 0){
        float dt = dinv[t];
#pragma unroll
        for (int r = 0; r < 4; ++r){
          int b = b_base + (lq<<2) + r;
          int f = (q<<4) + lrow;
          size_t o = ((size_t)b << 14) + (t << 7) + f;
          float ov = accL[r] + ob;
          lossAcc += fabsf(values[o] - ov) * masks[o] * dt;
        }
      }
    }

    // publish gates to LDS (C layout: row=(lane>>4)*4+r, col=lane&15)
#pragma unroll
    for (int r = 0; r < 4; ++r){
      int row = (lq<<2) + r;
      gl[((wv<<4) + row)*33 + lrow]      = acc0[r] + bias0;
      gl[((wv<<4) + row)*33 + 16 + lrow] = acc1[r] + bias1;
    }
    __syncthreads();

    // cell update: 512 elems [16 rows x 32 cols], 2 per thread
#pragma unroll
    for (int pp = 0; pp < 2; ++pp){
      int e = tid + (pp<<8);
      int row = e >> 5, col = e & 31;
      float zi = gl[row*33 + col];
      float zf = gl[(16+row)*33 + col];
      float zg = gl[(32+row)*33 + col];
      float zo = gl[(48+row)*33 + col];
      float cp = pp ? c1 : c0;
      float cn = sigm(zf)*cp + sigm(zi)*tanh_(zg);
      float hn = sigm(zo)*tanh_(cn);
      if (pp) c1 = cn; else c0 = cn;
      int b = b_base + row, j = j_base + col;
      if (t < NSTEP-1){
        h_buf[((((t+1)&1)*B_ + b) << 8) + j] = (f16)hn;
      } else {
        d_out[(b<<8) + j] = hn;               // h, fp32 from registers
        d_out[(1<<17) + (b<<8) + j] = cn;     // c
      }
    }

    if (t < NSTEP-1){
      // __syncthreads drains vmcnt(0) for every wave -> all h stores of this
      // WG are in (same-XCD) L2 before tid0's flag RMW issues after the
      // barrier. RELAXED: no L2 writeback/invalidate in the hot loop.
      __syncthreads();
      if (tid == 0)
        __hip_atomic_fetch_add(&flags[(((t+1)<<5) + gid)*FLAG_STRIDE], 1u,
                               __ATOMIC_RELAXED, __HIP_MEMORY_SCOPE_AGENT);
    } else {
      __syncthreads();
    }
  }

  // loss terms 0..125 reduction (wave 0 holds them)
  if (wv == 0){
#pragma unroll
    for (int off = 32; off > 0; off >>= 1)
      lossAcc += __shfl_down(lossAcc, off, 64);
    if (lane == 0) atomicAdd(loss_accum, lossAcc);
  }
}

// ---------------------------------------------------------------------------
__global__ __launch_bounds__(256) void kepi(
    const float* __restrict__ h_out, const float* __restrict__ outW,
    const float* __restrict__ outb, const float* __restrict__ values,
    const float* __restrict__ masks, float* __restrict__ num_final)
{
  int idx = blockIdx.x*256 + threadIdx.x;   // 65536 = 512*128
  int b = idx >> 7, f = idx & 127;
  const float* hr = h_out + (b << 8);
  const float* wr = outW + (f << 8);
  float s0 = 0.f, s1 = 0.f, s2 = 0.f, s3 = 0.f;
  for (int j = 0; j < 256; j += 4){
    s0 += hr[j]   * wr[j];
    s1 += hr[j+1] * wr[j+1];
    s2 += hr[j+2] * wr[j+2];
    s3 += hr[j+3] * wr[j+3];
  }
  float s = s0 + s1 + s2 + s3 + outb[f];
  size_t o = ((size_t)b << 14) + (127 << 7) + f;
  float term = fabsf(values[o] - s) * masks[o];
  __shared__ float red[256];
  red[threadIdx.x] = term; __syncthreads();
  for (int off = 128; off > 0; off >>= 1){
    if (threadIdx.x < off) red[threadIdx.x] += red[threadIdx.x + off];
    __syncthreads();
  }
  if (threadIdx.x == 0) atomicAdd(num_final, red[0]);
}

__global__ void kfin(const float* __restrict__ loss_accum,
                     const float* __restrict__ num_final,
                     const float* __restrict__ dinv, float* __restrict__ d_out)
{
  d_out[1<<18] = loss_accum[0] + num_final[0] * dinv[127];
}

// ---------------------------------------------------------------------------
extern "C" void kernel_launch(void* const* d_in, const int* in_sizes, int n_in,
                              void* d_out, int out_size, void* d_ws, size_t ws_size,
                              hipStream_t stream)
{
  const float* values = (const float*)d_in[0];
  const float* masks  = (const float*)d_in[1];
  const float* deltas = (const float*)d_in[2];
  const float* featW  = (const float*)d_in[3];
  const float* featb  = (const float*)d_in[4];
  const float* tempW  = (const float*)d_in[5];
  const float* tempb  = (const float*)d_in[6];
  const float* decW   = (const float*)d_in[7];
  const float* decb   = (const float*)d_in[8];
  const float* Wih    = (const float*)d_in[9];
  const float* Whh    = (const float*)d_in[10];
  const float* bih    = (const float*)d_in[11];
  const float* bhh    = (const float*)d_in[12];
  const float* outW   = (const float*)d_in[13];
  const float* outb   = (const float*)d_in[14];
  float* out = (float*)d_out;
  char* ws = (char*)d_ws;

  f16* Wt    = (f16*)(ws + 0);                 // 1 MB
  f16* oWh   = (f16*)(ws + 1048576);           // 64 KB
  float* fWT = (float*)(ws + 1114112);         // 64 KB
  float* tWm = (float*)(ws + 1179648);         // 64 KB
  float* dWT = (float*)(ws + 1245184);         // 128 KB
  float* dinv = (float*)(ws + 1376256);        // 512 B
  unsigned int* flags = (unsigned int*)(ws + 1376768);  // 256 KB (padded lines)
  float* accums = (float*)(ws + 1638912);      // [0]=loss_accum [1]=num_final
  f16* h_buf = (f16*)(ws + 1639424);           // 512 KB ping-pong
  f16* x_all = (f16*)(ws + 2163712);           // 32 MB
  f16* g_all = (f16*)(ws + 35718144);          // 32 MB  (end ~69 MB)

  kprep<<<256, 256, 0, stream>>>(Wih, Whh, outW, featW, tempW, decW,
                                 Wt, oWh, fWT, tWm, dWT, flags, accums);
  kdenom<<<128, 256, 0, stream>>>(masks, dinv);
  k1<<<512, 256, 0, stream>>>(values, masks, fWT, tWm, featb, tempb, x_all);
  k2<<<512, 256, 0, stream>>>(deltas, dWT, decb, g_all);

  const int SLDS = 128*KP*2 + 16*OWP*2 + 64*33*4;   // 150016 B
  hipFuncSetAttribute((const void*)kscan, hipFuncAttributeMaxDynamicSharedMemorySize, SLDS);
  kscan<<<256, 256, SLDS, stream>>>(x_all, g_all, Wt, oWh, bih, bhh, outb,
                                    values, masks, dinv, h_buf, flags,
                                    accums, out);

  kepi<<<256, 256, 0, stream>>>(out, outW, outb, values, masks, accums + 1);
  kfin<<<1, 1, 0, stream>>>(accums, accums + 1, dinv, out);
}